// Round 6
// baseline (398.657 us; speedup 1.0000x reference)
//
#include <hip/hip_runtime.h>

#define FDIM 512
#define CDIM 64
#define NLEAF 1024
#define MAT (FDIM * CDIM)            /* 32768 floats per node */
#define OUT_LOGITS (NLEAF * CDIM)    /* 65536 */
#define WS_REG (4096 * 64)           /* float offset of reg partials in ws */

__device__ __forceinline__ float abs4(const float4 v) {
    return fabsf(v.x) + fabsf(v.y) + fabsf(v.z) + fabsf(v.w);
}
__device__ __forceinline__ float sq4(const float4 v) {
    return v.x * v.x + v.y * v.y + v.z * v.z + v.w * v.w;
}

// Stream this thread's 8f x 4c tile of one node: 8 independent float4 loads
// issued as one burst, then FMAs. MODE: 1 = L1*scale, 2 = squared (root).
template<int MODE>
__device__ __forceinline__ void node_q(const float* __restrict__ p,
                                       const float4 xr[2],
                                       float4& acc, float& rl1, float& rsq,
                                       float scale)
{
    float4 d[8];
#pragma unroll
    for (int i = 0; i < 8; ++i)
        d[i] = *(const float4*)(p + (size_t)i * CDIM);
#pragma unroll
    for (int i = 0; i < 8; ++i) {
        const float4 xv = xr[i >> 2];
        const float xs = (i & 3) == 0 ? xv.x : (i & 3) == 1 ? xv.y
                       : (i & 3) == 2 ? xv.z : xv.w;
        acc.x += xs * d[i].x;
        acc.y += xs * d[i].y;
        acc.z += xs * d[i].z;
        acc.w += xs * d[i].w;
        if (MODE == 1) rl1 = fmaf(abs4(d[i]), scale, rl1);
        if (MODE == 2) rsq += sq4(d[i]);
    }
}

// ---------------------------------------------------------------------------
// One block = (leaf) x (128-wide f-quarter). 4096 blocks, 256 threads.
// Same cache topology as the round-3 winner (blocks with equal fs read the
// SAME full 32KB ancestor slabs root->leaf in phase), but 4x the blocks:
// 16 blocks/CU target, VGPR<=64 -> up to 32 waves/CU for latency hiding.
// Thread tile: 8 f-rows x 4 c-cols; 48 independent float4 loads per thread.
// ---------------------------------------------------------------------------
__global__ __launch_bounds__(256, 8) void k_stream(const float* __restrict__ x,
                                                   const float* __restrict__ deltas,
                                                   const float* __restrict__ heights,
                                                   float* __restrict__ ws)
{
    __shared__ float red[4][68];
    __shared__ float rr[4];

    const int tid = threadIdx.x;
    const int bid = blockIdx.x;
    // XCD k = bid&7 owns leaves [128k, 128k+128) for all 4 f-quarters
    const int k  = bid & 7;
    const int t  = bid >> 3;            // 0..511
    const int fs = t & 3;               // f-quarter
    const int b  = (k << 7) | (t >> 2); // leaf 0..1023
    const int fg = tid >> 4;            // 0..15 (8 f each)
    const int cq = tid & 15;            // c-quad
    const int f0 = fs * 128 + fg * 8;

    // x fragment: 8 floats (2 float4)
    float4 xr[2];
    xr[0] = *(const float4*)(x + (size_t)b * FDIM + f0);
    xr[1] = *(const float4*)(x + (size_t)b * FDIM + f0 + 4);

    // path nodes and reg scales (0 = this leaf doesn't own the node's reg)
    const int n1 = 1 + (b >> 8), n2 = 5 + (b >> 6), n3 = 21 + (b >> 4);
    const int n4 = 85 + (b >> 2), n5 = 341 + b;
    const float h0 = heights[0],  h1 = heights[n1], h2 = heights[n2];
    const float h3 = heights[n3], h4 = heights[n4], h5 = heights[n5];
    const float s1 = ((b & 255) == 0) ? 1.f / fmaxf(fabsf(h1 - h0), 1e-7f) : 0.f;
    const float s2 = ((b & 63)  == 0) ? 1.f / fmaxf(fabsf(h2 - h1), 1e-7f) : 0.f;
    const float s3 = ((b & 15)  == 0) ? 1.f / fmaxf(fabsf(h3 - h2), 1e-7f) : 0.f;
    const float s4 = ((b & 3)   == 0) ? 1.f / fmaxf(fabsf(h4 - h3), 1e-7f) : 0.f;
    const float s5 = 1.f / fmaxf(fabsf(h5 - h4), 1e-7f);

    const size_t toff = (size_t)f0 * CDIM + (size_t)cq * 4;
    float4 acc = make_float4(0.f, 0.f, 0.f, 0.f);
    float rl1 = 0.f, rsq = 0.f;

    // branchless root->leaf stream: 6 nodes x 8 independent float4 loads
    node_q<2>(deltas + toff,                    xr, acc, rl1, rsq, 0.f);
    node_q<1>(deltas + (size_t)n1 * MAT + toff, xr, acc, rl1, rsq, s1);
    node_q<1>(deltas + (size_t)n2 * MAT + toff, xr, acc, rl1, rsq, s2);
    node_q<1>(deltas + (size_t)n3 * MAT + toff, xr, acc, rl1, rsq, s3);
    node_q<1>(deltas + (size_t)n4 * MAT + toff, xr, acc, rl1, rsq, s4);
    node_q<1>(deltas + (size_t)n5 * MAT + toff, xr, acc, rl1, rsq, s5);

    // ---- reduce acc over the 4 fg per wave (lane bits 4,5)
    acc.x += __shfl_xor(acc.x, 16, 64);  acc.x += __shfl_xor(acc.x, 32, 64);
    acc.y += __shfl_xor(acc.y, 16, 64);  acc.y += __shfl_xor(acc.y, 32, 64);
    acc.z += __shfl_xor(acc.z, 16, 64);  acc.z += __shfl_xor(acc.z, 32, 64);
    acc.w += __shfl_xor(acc.w, 16, 64);  acc.w += __shfl_xor(acc.w, 32, 64);

    const int w = tid >> 6, lane = tid & 63;
    if (lane < 16)
        *(float4*)(&red[w][cq * 4]) = acc;   // red[w][c] holds wave partial

    // ---- reg partial: wave butterfly -> LDS
    float r2 = rl1 + ((b == 0) ? rsq : 0.f);
#pragma unroll
    for (int off = 1; off < 64; off <<= 1) r2 += __shfl_xor(r2, off, 64);
    if (lane == 0) rr[w] = r2;
    __syncthreads();

    // ---- write 64 logit partials (coalesced) + reg partial
    if (tid < 64) {
        const float v = red[0][tid] + red[1][tid] + red[2][tid] + red[3][tid];
        ws[(size_t)(b * 4 + fs) * 64 + tid] = v;
    }
    if (tid == 64)
        ws[WS_REG + b * 4 + fs] = rr[0] + rr[1] + rr[2] + rr[3];
}

// ---------------------------------------------------------------------------
// Finish: sum the 4 f-quarter partials per leaf, softmax, write out.
// One 64-lane wave per leaf row. 256 blocks x 256 threads.
// ---------------------------------------------------------------------------
__global__ __launch_bounds__(256) void k_finish(const float* __restrict__ ws,
                                                float* __restrict__ out)
{
    const int l = blockIdx.x * 4 + (threadIdx.x >> 6);
    const int c = threadIdx.x & 63;
    const float* p = ws + (size_t)l * 256;
    float v = p[c] + p[64 + c] + p[128 + c] + p[192 + c];
    float m = v;
#pragma unroll
    for (int off = 32; off > 0; off >>= 1) m = fmaxf(m, __shfl_xor(m, off, 64));
    const float e = expf(v - m);
    float s = e;
#pragma unroll
    for (int off = 32; off > 0; off >>= 1) s += __shfl_xor(s, off, 64);
    out[(size_t)l * CDIM + c] = e / s;
}

// ---------------------------------------------------------------------------
// Sum the 4096 reg partials -> out[OUT_LOGITS]
// ---------------------------------------------------------------------------
__global__ __launch_bounds__(256) void k_regsum(const float* __restrict__ ws,
                                                float* __restrict__ out)
{
    __shared__ float r[4];
    const int tid = threadIdx.x;
    const float* p = ws + WS_REG;
    float v = 0.f;
#pragma unroll
    for (int i = 0; i < 16; ++i) v += p[i * 256 + tid];
#pragma unroll
    for (int off = 1; off < 64; off <<= 1) v += __shfl_xor(v, off, 64);
    if ((tid & 63) == 0) r[tid >> 6] = v;
    __syncthreads();
    if (tid == 0) out[OUT_LOGITS] = r[0] + r[1] + r[2] + r[3];
}

extern "C" void kernel_launch(void* const* d_in, const int* in_sizes, int n_in,
                              void* d_out, int out_size, void* d_ws, size_t ws_size,
                              hipStream_t stream)
{
    const float* x       = (const float*)d_in[0];
    const float* deltas  = (const float*)d_in[1];
    const float* heights = (const float*)d_in[2];
    float* out = (float*)d_out;
    float* ws  = (float*)d_ws;

    k_stream<<<4096, 256, 0, stream>>>(x, deltas, heights, ws);
    k_finish<<<256, 256, 0, stream>>>(ws, out);
    k_regsum<<<1, 256, 0, stream>>>(ws, out);
}

// Round 7
// 366.813 us; speedup vs baseline: 1.0868x; 1.0868x over previous
//
#include <hip/hip_runtime.h>

#define FDIM 512
#define CDIM 64
#define NLEAF 1024
#define MAT (FDIM * CDIM)            /* 32768 floats per node */
#define OUT_LOGITS (NLEAF * CDIM)    /* 65536 */
#define WS_REG (NLEAF * CDIM)        /* float offset of reg partials in ws */

__device__ __forceinline__ float abs4(const float4 v) {
    return fabsf(v.x) + fabsf(v.y) + fabsf(v.z) + fabsf(v.w);
}
__device__ __forceinline__ float sq4(const float4 v) {
    return v.x * v.x + v.y * v.y + v.z * v.z + v.w * v.w;
}

// Stream this thread's 16f x 4c tile of one node (16 float4 loads, 4-deep
// bursts, branchless). MODE: 1 = L1*scale, 2 = squared (root).
template<int MODE>
__device__ __forceinline__ void node_c(const float* __restrict__ p,
                                       const float4 xr[4],
                                       float4& acc, float& rl1, float& rsq,
                                       float scale)
{
#pragma unroll
    for (int j = 0; j < 4; ++j) {
        const float* q = p + (size_t)(4 * j) * CDIM;
        const float4 d0 = *(const float4*)(q);
        const float4 d1 = *(const float4*)(q + CDIM);
        const float4 d2 = *(const float4*)(q + 2 * CDIM);
        const float4 d3 = *(const float4*)(q + 3 * CDIM);
        if (MODE == 1) rl1 = fmaf(abs4(d0) + abs4(d1) + abs4(d2) + abs4(d3), scale, rl1);
        if (MODE == 2) rsq += sq4(d0) + sq4(d1) + sq4(d2) + sq4(d3);
        const float4 xv = xr[j];
        acc.x += xv.x * d0.x + xv.y * d1.x + xv.z * d2.x + xv.w * d3.x;
        acc.y += xv.x * d0.y + xv.y * d1.y + xv.z * d2.y + xv.w * d3.y;
        acc.z += xv.x * d0.z + xv.y * d1.z + xv.z * d2.z + xv.w * d3.z;
        acc.w += xv.x * d0.w + xv.y * d1.w + xv.z * d2.w + xv.w * d3.w;
    }
}

// ---------------------------------------------------------------------------
// One block = (leaf) x (c-half). 2048 blocks, 256 threads, 8 blocks/CU.
// Identical cache topology to the round-3 winner (full-f slab reads, blocks
// in phase root->leaf, 128-leaf contiguous range per XCD; both c-halves of a
// leaf dispatch-adjacent on the same XCD) but 2x the blocks and smaller
// per-thread state for deeper latency hiding. Thread tile: 16 f x 4 c;
// 96 float4 delta loads per thread, branchless.
// ---------------------------------------------------------------------------
__global__ __launch_bounds__(256, 4) void k_stream(const float* __restrict__ x,
                                                   const float* __restrict__ deltas,
                                                   const float* __restrict__ heights,
                                                   float* __restrict__ ws)
{
    __shared__ float red[4][32];
    __shared__ float rr[4];

    const int tid = threadIdx.x;
    const int bid = blockIdx.x;
    // XCD k owns leaves [128k, 128k+128), both c-halves adjacent in dispatch
    const int k  = bid & 7;
    const int t  = bid >> 3;            // 0..255
    const int b  = (k << 7) | (t >> 1); // leaf 0..1023
    const int ch = t & 1;               // c-half
    const int fg = tid >> 3;            // 0..31 (16 f each)
    const int cq = tid & 7;             // c-quad within half
    const int f0 = fg * 16;
    const int c0 = ch * 32 + cq * 4;

    // x fragment: 16 floats (4 float4)
    float4 xr[4];
#pragma unroll
    for (int i = 0; i < 4; ++i)
        xr[i] = *(const float4*)(x + (size_t)b * FDIM + f0 + 4 * i);

    // path nodes and reg scales (0 = this leaf doesn't own the node's reg)
    const int n1 = 1 + (b >> 8), n2 = 5 + (b >> 6), n3 = 21 + (b >> 4);
    const int n4 = 85 + (b >> 2), n5 = 341 + b;
    const float h0 = heights[0],  h1 = heights[n1], h2 = heights[n2];
    const float h3 = heights[n3], h4 = heights[n4], h5 = heights[n5];
    const float s1 = ((b & 255) == 0) ? 1.f / fmaxf(fabsf(h1 - h0), 1e-7f) : 0.f;
    const float s2 = ((b & 63)  == 0) ? 1.f / fmaxf(fabsf(h2 - h1), 1e-7f) : 0.f;
    const float s3 = ((b & 15)  == 0) ? 1.f / fmaxf(fabsf(h3 - h2), 1e-7f) : 0.f;
    const float s4 = ((b & 3)   == 0) ? 1.f / fmaxf(fabsf(h4 - h3), 1e-7f) : 0.f;
    const float s5 = 1.f / fmaxf(fabsf(h5 - h4), 1e-7f);

    const size_t toff = (size_t)f0 * CDIM + c0;
    float4 acc = make_float4(0.f, 0.f, 0.f, 0.f);
    float rl1 = 0.f, rsq = 0.f;

    // branchless root->leaf stream: 6 nodes x 16 float4 loads
    node_c<2>(deltas + toff,                    xr, acc, rl1, rsq, 0.f);
    node_c<1>(deltas + (size_t)n1 * MAT + toff, xr, acc, rl1, rsq, s1);
    node_c<1>(deltas + (size_t)n2 * MAT + toff, xr, acc, rl1, rsq, s2);
    node_c<1>(deltas + (size_t)n3 * MAT + toff, xr, acc, rl1, rsq, s3);
    node_c<1>(deltas + (size_t)n4 * MAT + toff, xr, acc, rl1, rsq, s4);
    node_c<1>(deltas + (size_t)n5 * MAT + toff, xr, acc, rl1, rsq, s5);

    // ---- reduce acc over the 8 fg per wave (lane bits 3,4,5)
    acc.x += __shfl_xor(acc.x, 8, 64); acc.x += __shfl_xor(acc.x, 16, 64); acc.x += __shfl_xor(acc.x, 32, 64);
    acc.y += __shfl_xor(acc.y, 8, 64); acc.y += __shfl_xor(acc.y, 16, 64); acc.y += __shfl_xor(acc.y, 32, 64);
    acc.z += __shfl_xor(acc.z, 8, 64); acc.z += __shfl_xor(acc.z, 16, 64); acc.z += __shfl_xor(acc.z, 32, 64);
    acc.w += __shfl_xor(acc.w, 8, 64); acc.w += __shfl_xor(acc.w, 16, 64); acc.w += __shfl_xor(acc.w, 32, 64);

    const int w = tid >> 6, lane = tid & 63;
    if (lane < 8)
        *(float4*)(&red[w][cq * 4]) = acc;   // red[w][c'] = wave partial, c' 0..31

    // ---- reg partial: wave butterfly -> LDS
    float r2 = rl1 + ((b == 0) ? rsq : 0.f);
#pragma unroll
    for (int off = 1; off < 64; off <<= 1) r2 += __shfl_xor(r2, off, 64);
    if (lane == 0) rr[w] = r2;
    __syncthreads();

    // ---- write the 32 complete logit entries this block owns (no reduction
    //      across blocks needed: f is complete within the block)
    if (tid < 32)
        ws[(size_t)b * CDIM + ch * 32 + tid] =
            red[0][tid] + red[1][tid] + red[2][tid] + red[3][tid];
    if (tid == 32)
        ws[WS_REG + b * 2 + ch] = rr[0] + rr[1] + rr[2] + rr[3];
}

// ---------------------------------------------------------------------------
// Finish: softmax per leaf row (logits already complete in ws). One 64-lane
// wave per row; 256 blocks x 256 threads.
// ---------------------------------------------------------------------------
__global__ __launch_bounds__(256) void k_finish(const float* __restrict__ ws,
                                                float* __restrict__ out)
{
    const int l = blockIdx.x * 4 + (threadIdx.x >> 6);
    const int c = threadIdx.x & 63;
    const float v = ws[(size_t)l * CDIM + c];
    float m = v;
#pragma unroll
    for (int off = 32; off > 0; off >>= 1) m = fmaxf(m, __shfl_xor(m, off, 64));
    const float e = expf(v - m);
    float s = e;
#pragma unroll
    for (int off = 32; off > 0; off >>= 1) s += __shfl_xor(s, off, 64);
    out[(size_t)l * CDIM + c] = e / s;
}

// ---------------------------------------------------------------------------
// Sum the 2048 reg partials -> out[OUT_LOGITS]
// ---------------------------------------------------------------------------
__global__ __launch_bounds__(256) void k_regsum(const float* __restrict__ ws,
                                                float* __restrict__ out)
{
    __shared__ float r[4];
    const int tid = threadIdx.x;
    const float* p = ws + WS_REG;
    float v = 0.f;
#pragma unroll
    for (int i = 0; i < 8; ++i) v += p[i * 256 + tid];
#pragma unroll
    for (int off = 1; off < 64; off <<= 1) v += __shfl_xor(v, off, 64);
    if ((tid & 63) == 0) r[tid >> 6] = v;
    __syncthreads();
    if (tid == 0) out[OUT_LOGITS] = r[0] + r[1] + r[2] + r[3];
}

extern "C" void kernel_launch(void* const* d_in, const int* in_sizes, int n_in,
                              void* d_out, int out_size, void* d_ws, size_t ws_size,
                              hipStream_t stream)
{
    const float* x       = (const float*)d_in[0];
    const float* deltas  = (const float*)d_in[1];
    const float* heights = (const float*)d_in[2];
    float* out = (float*)d_out;
    float* ws  = (float*)d_ws;

    k_stream<<<2048, 256, 0, stream>>>(x, deltas, heights, ws);
    k_finish<<<256, 256, 0, stream>>>(ws, out);
    k_regsum<<<1, 256, 0, stream>>>(ws, out);
}

// Round 8
// 67.218 us; speedup vs baseline: 5.9308x; 5.4571x over previous
//
#include <hip/hip_runtime.h>

#define FDIM 512
#define CDIM 64
#define NLEAF 1024
#define MAT (FDIM * CDIM)          /* 32768 floats per node */
#define OUT_LOGITS (NLEAF * CDIM)  /* 65536 */

__device__ __forceinline__ float abs4(const float4 v) {
    return fabsf(v.x) + fabsf(v.y) + fabsf(v.z) + fabsf(v.w);
}
__device__ __forceinline__ float sq4(const float4 v) {
    return v.x * v.x + v.y * v.y + v.z * v.z + v.w * v.w;
}

// MODE: 0 = no reg accumulation, 1 = L1*scale, 2 = squared (root)
// 4 bursts of 8 independent float4 loads (named locals -> registers, never
// an indexed array), consumed immediately after the burst.
template<int MODE>
__device__ __forceinline__ void stream_node(const float* __restrict__ dbase,
                                            const float4* __restrict__ xr,
                                            float4& acc, float& rsum, float s)
{
#pragma unroll
    for (int h = 0; h < 4; ++h) {
        const float* q = dbase + (size_t)(8 * h) * CDIM;
        const float4 d0 = *(const float4*)(q);
        const float4 d1 = *(const float4*)(q + CDIM);
        const float4 d2 = *(const float4*)(q + 2 * CDIM);
        const float4 d3 = *(const float4*)(q + 3 * CDIM);
        const float4 d4 = *(const float4*)(q + 4 * CDIM);
        const float4 d5 = *(const float4*)(q + 5 * CDIM);
        const float4 d6 = *(const float4*)(q + 6 * CDIM);
        const float4 d7 = *(const float4*)(q + 7 * CDIM);
        const float4 xa = xr[2 * h];
        const float4 xb = xr[2 * h + 1];
        acc.x += xa.x * d0.x + xa.y * d1.x + xa.z * d2.x + xa.w * d3.x
               + xb.x * d4.x + xb.y * d5.x + xb.z * d6.x + xb.w * d7.x;
        acc.y += xa.x * d0.y + xa.y * d1.y + xa.z * d2.y + xa.w * d3.y
               + xb.x * d4.y + xb.y * d5.y + xb.z * d6.y + xb.w * d7.y;
        acc.z += xa.x * d0.z + xa.y * d1.z + xa.z * d2.z + xa.w * d3.z
               + xb.x * d4.z + xb.y * d5.z + xb.z * d6.z + xb.w * d7.z;
        acc.w += xa.x * d0.w + xa.y * d1.w + xa.z * d2.w + xa.w * d3.w
               + xb.x * d4.w + xb.y * d5.w + xb.z * d6.w + xb.w * d7.w;
        if (MODE == 1)
            rsum = fmaf(abs4(d0) + abs4(d1) + abs4(d2) + abs4(d3)
                      + abs4(d4) + abs4(d5) + abs4(d6) + abs4(d7), s, rsum);
        if (MODE == 2)
            rsum += sq4(d0) + sq4(d1) + sq4(d2) + sq4(d3)
                  + sq4(d4) + sq4(d5) + sq4(d6) + sq4(d7);
    }
}

// ---------------------------------------------------------------------------
// One block per leaf (round-3 winner structure, unchanged): streams the 6
// path deltas (768 KB) once; thread tile 32 f x 4 c; x slice in registers;
// fused regularization + softmax; no logit atomics. Only change vs round 3:
// 8-deep load bursts inside stream_node + sched_barrier between nodes to
// bound scheduler hoisting (round-7 spill pathology).
// ---------------------------------------------------------------------------
__global__ __launch_bounds__(256, 4) void k_fused(const float* __restrict__ x,
                                                  const float* __restrict__ deltas,
                                                  const float* __restrict__ heights,
                                                  float* __restrict__ out,
                                                  float* __restrict__ ws)
{
    __shared__ float red[256 * 4];
    __shared__ float rred[4];

    const int bid = blockIdx.x;
    const int b   = ((bid & 7) << 7) | (bid >> 3);   // XCD-swizzled leaf id
    const int tid = threadIdx.x;
    const int fg  = tid >> 4;    // f-slice base = fg*32
    const int cq  = tid & 15;    // c-quad -> c = cq*4 .. cq*4+3

    float4 xr[8];
    {
        const float* xb = x + (size_t)b * FDIM + fg * 32;
#pragma unroll
        for (int i = 0; i < 8; ++i) xr[i] = *(const float4*)(xb + i * 4);
    }

    float4 acc = make_float4(0.f, 0.f, 0.f, 0.f);
    float rsum = 0.f;
    const size_t toff = (size_t)fg * 32 * CDIM + (size_t)cq * 4;

    // walk root -> leaf (co-resident blocks stay in phase for L2 reuse)
#pragma unroll
    for (int d = 0; d < 6; ++d) {
        const int shift = 2 * (5 - d);
        const int start = ((1 << (2 * d)) - 1) / 3;      // 0,1,5,21,85,341
        const int node  = start + (b >> shift);
        const float* dbase = deltas + (size_t)node * MAT + toff;
        const bool doReg = (b & ((1 << shift) - 1)) == 0;
        if (d == 0) {
            if (doReg) stream_node<2>(dbase, xr, acc, rsum, 1.f);
            else       stream_node<0>(dbase, xr, acc, rsum, 0.f);
        } else {
            if (doReg) {
                const int par = (node - 1) >> 2;
                const float s = 1.f / fmaxf(fabsf(heights[node] - heights[par]), 1e-7f);
                stream_node<1>(dbase, xr, acc, rsum, s);
            } else {
                stream_node<0>(dbase, xr, acc, rsum, 0.f);
            }
        }
        __builtin_amdgcn_sched_barrier(0);   // bound cross-node load hoisting
    }

    // ---- logits: per-thread float4 partials -> LDS -> 64-lane reduce
    *(float4*)(red + tid * 4) = acc;      // flat index = fg*64 + c

    // ---- regularization partial: block reduce -> ws[bid]
#pragma unroll
    for (int off = 1; off < 64; off <<= 1) rsum += __shfl_xor(rsum, off, 64);
    if ((tid & 63) == 0) rred[tid >> 6] = rsum;
    __syncthreads();
    if (tid == 0) ws[bid] = rred[0] + rred[1] + rred[2] + rred[3];

    // ---- softmax on wave 0 (threads 0..63 hold logits c = tid)
    if (tid < CDIM) {
        float v = 0.f;
#pragma unroll
        for (int g = 0; g < 16; ++g) v += red[g * 64 + tid];
        float m = v;
#pragma unroll
        for (int off = 32; off > 0; off >>= 1) m = fmaxf(m, __shfl_xor(m, off, 64));
        const float e = expf(v - m);
        float s2 = e;
#pragma unroll
        for (int off = 32; off > 0; off >>= 1) s2 += __shfl_xor(s2, off, 64);
        out[(size_t)b * CDIM + tid] = e / s2;
    }
}

// ---------------------------------------------------------------------------
// Sum the 1024 per-block regularization partials -> out[OUT_LOGITS]
// ---------------------------------------------------------------------------
__global__ __launch_bounds__(256) void k_regsum(const float* __restrict__ ws,
                                                float* __restrict__ out)
{
    __shared__ float r[4];
    const int tid = threadIdx.x;
    float v = ws[tid] + ws[256 + tid] + ws[512 + tid] + ws[768 + tid];
#pragma unroll
    for (int off = 1; off < 64; off <<= 1) v += __shfl_xor(v, off, 64);
    if ((tid & 63) == 0) r[tid >> 6] = v;
    __syncthreads();
    if (tid == 0) out[OUT_LOGITS] = r[0] + r[1] + r[2] + r[3];
}

extern "C" void kernel_launch(void* const* d_in, const int* in_sizes, int n_in,
                              void* d_out, int out_size, void* d_ws, size_t ws_size,
                              hipStream_t stream)
{
    const float* x       = (const float*)d_in[0];
    const float* deltas  = (const float*)d_in[1];
    const float* heights = (const float*)d_in[2];
    float* out = (float*)d_out;
    float* ws  = (float*)d_ws;

    k_fused<<<NLEAF, 256, 0, stream>>>(x, deltas, heights, out, ws);
    k_regsum<<<1, 256, 0, stream>>>(ws, out);
}